// Round 6
// baseline (555.809 us; speedup 1.0000x reference)
//
#include <hip/hip_runtime.h>
#include <hip/hip_bf16.h>
#include <math.h>

#define NB 8
#define TT 2048
#define SS 2048
#define CC 1024
#define EE 1024

typedef __attribute__((ext_vector_type(8))) short short8;
typedef __attribute__((ext_vector_type(4))) float f32x4;

__device__ __forceinline__ unsigned short f2bf(float f) {
  unsigned u = __builtin_bit_cast(unsigned, f);
  u += 0x7fffu + ((u >> 16) & 1u);          // RNE
  return (unsigned short)(u >> 16);
}
__device__ __forceinline__ float bf2f(unsigned short h) {
  unsigned u = ((unsigned)h) << 16;
  return __builtin_bit_cast(float, u);
}
__device__ __forceinline__ void gload16(const void* g, void* l) {
  __builtin_amdgcn_global_load_lds((const __attribute__((address_space(1))) void*)g,
                                   (__attribute__((address_space(3))) void*)l, 16, 0, 0);
}
__device__ __forceinline__ unsigned ldsoff(const void* p) {
  return (unsigned)(size_t)(const __attribute__((address_space(3))) char*)p;
}
__device__ __forceinline__ short8 ds128(unsigned off) {
  short8 r;
  asm volatile("ds_read_b128 %0, %1" : "=v"(r) : "v"(off));
  return r;
}
// XOR swizzle: bits 4-6 ^= bits 7-9 (involution)
__device__ __forceinline__ int swzi(int x) { return x ^ (((x >> 7) & 7) << 4); }

#define WAITV(N) asm volatile("s_waitcnt vmcnt(" #N ")" ::: "memory")
#define WAITL(N) asm volatile("s_waitcnt lgkmcnt(" #N ")" ::: "memory")
#define BAR() __builtin_amdgcn_s_barrier()
#define SCH0() __builtin_amdgcn_sched_barrier(0)
#define PRIO1() __builtin_amdgcn_s_setprio(1)
#define PRIO0() __builtin_amdgcn_s_setprio(0)
#define MF(a_, b_, c_) __builtin_amdgcn_mfma_f32_16x16x32_bf16(a_, b_, c_, 0, 0, 0)

// chunked bijective XCD swizzle: physical pid -> logical L so each XCD gets a
// contiguous chunk of logical ids. Requires nwg % 8 == 0 (all our grids).
__device__ __forceinline__ int xcd_logical() {
  int gx = gridDim.x, gy = gridDim.y, gz = gridDim.z;
  int pid = blockIdx.x + gx * (blockIdx.y + gy * blockIdx.z);
  int q = (gx * gy * gz) >> 3;
  return (pid & 7) * q + (pid >> 3);
}

// ---------------- split f32 -> bf16 hi/lo ----------------
__global__ __launch_bounds__(256) void k_split(const float* __restrict__ in,
    unsigned short* __restrict__ hi, unsigned short* __restrict__ lo, long n4) {
  long i = (long)blockIdx.x * blockDim.x + threadIdx.x;
  long stride = (long)gridDim.x * blockDim.x;
  for (; i < n4; i += stride) {
    float4 v = ((const float4*)in)[i];
    float f[4] = {v.x, v.y, v.z, v.w};
    unsigned short hh[4], ll[4];
#pragma unroll
    for (int j = 0; j < 4; ++j) {
      hh[j] = f2bf(f[j]);
      ll[j] = f2bf(f[j] - bf2f(hh[j]));
    }
    ushort4 h; h.x = hh[0]; h.y = hh[1]; h.z = hh[2]; h.w = hh[3];
    ushort4 l; l.x = ll[0]; l.y = ll[1]; l.z = ll[2]; l.w = ll[3];
    ((ushort4*)hi)[i] = h;
    ((ushort4*)lo)[i] = l;
  }
}

// ---------------- f32 -> bf16 convert ----------------
__global__ __launch_bounds__(256) void k_conv(const float* __restrict__ in,
    unsigned short* __restrict__ out, long n4) {
  long i = (long)blockIdx.x * blockDim.x + threadIdx.x;
  long stride = (long)gridDim.x * blockDim.x;
  for (; i < n4; i += stride) {
    float4 v = ((const float4*)in)[i];
    ushort4 h; h.x = f2bf(v.x); h.y = f2bf(v.y); h.z = f2bf(v.z); h.w = f2bf(v.w);
    ((ushort4*)out)[i] = h;
  }
}

// ---------------- batched transpose f32[R,C] -> bf16 [C,R] (hi (+lo)) ----------------
template <bool SPLIT>
__global__ __launch_bounds__(256) void k_transpose(const float* __restrict__ in,
    unsigned short* __restrict__ hi, unsigned short* __restrict__ lo, int R, int C) {
  __shared__ float tile[64][65];
  int b = blockIdx.z;
  const float* inb = in + (size_t)b * R * C;
  int r0 = blockIdx.y * 64, c0 = blockIdx.x * 64;
  int t = threadIdx.x;
  int tr = t >> 4;
  int tc = (t & 15) * 4;
#pragma unroll
  for (int i = 0; i < 4; ++i) {
    int r = tr + i * 16;
    float4 v = *(const float4*)(inb + (size_t)(r0 + r) * C + (c0 + tc));
    tile[r][tc] = v.x; tile[r][tc + 1] = v.y; tile[r][tc + 2] = v.z; tile[r][tc + 3] = v.w;
  }
  __syncthreads();
  size_t ob = (size_t)b * R * C;
#pragma unroll
  for (int i = 0; i < 4; ++i) {
    int c = tr + i * 16;
    unsigned short hh[4], ll[4];
#pragma unroll
    for (int j = 0; j < 4; ++j) {
      float f = tile[tc + j][c];
      hh[j] = f2bf(f);
      if (SPLIT) ll[j] = f2bf(f - bf2f(hh[j]));
    }
    ushort4 h; h.x = hh[0]; h.y = hh[1]; h.z = hh[2]; h.w = hh[3];
    *(ushort4*)(hi + ob + (size_t)(c0 + c) * R + (r0 + tc)) = h;
    if (SPLIT) {
      ushort4 l; l.x = ll[0]; l.y = ll[1]; l.z = ll[2]; l.w = ll[3];
      *(ushort4*)(lo + ob + (size_t)(c0 + c) * R + (r0 + tc)) = l;
    }
  }
}

// ================= plain bf16 GEMM, 256x256 tile, BK=64, 2 phases/tile =================
// Per phase: {WAITV(4); BAR; 12 ds_reads + stage 4 units; BAR; lgkm(0); 32 MFMA}.
// Stage order per tile: A.ks0,B.ks0 (ph1), A.ks1,B.ks1 (ph2) -> 8 units in flight max.
template <int EPI>
__global__ __launch_bounds__(512, 2) void k_gemm8(
    const unsigned short* __restrict__ A, const unsigned short* __restrict__ B,
    int N, int K, long sA, long sB, long sC,
    const float* __restrict__ bias, const float* __restrict__ addend,
    float* __restrict__ outF, unsigned short* __restrict__ outH, float scale) {
  extern __shared__ char lds[];
  const int tid = threadIdx.x, wave = tid >> 6, lane = tid & 63;
  int L = xcd_logical();
  const int n0 = (L % gridDim.x) * 256;
  int tmpL = L / gridDim.x;
  const int m0 = (tmpL % gridDim.y) * 256;
  const int b = tmpL / gridDim.y;
  const int wm = wave >> 2, wn = wave & 3;
  const unsigned short* gA = A + (size_t)b * sA + (size_t)m0 * K;
  const unsigned short* gB = B + (size_t)b * sB + (size_t)n0 * K;
  const unsigned ldsB = ldsoff(lds);

  int srow[2], sk8[2];
#pragma unroll
  for (int s = 0; s < 2; ++s) {
    int l = swzi((s * 512 + tid) * 16);
    srow[s] = l >> 6;
    sk8[s] = (l >> 4) & 3;
  }
  const int aR = wm * 128 + (lane & 15);
  const int bR = wn * 64 + (lane & 15);
  const int kB = (lane >> 4) * 16;
  const int nkt = K >> 6;

  f32x4 acc[8][4] = {};

  auto STG = [&](int t, int tensor, int ks) {
    const unsigned short* g = tensor ? gB : gA;
    char* dst = lds + (t & 1) * 65536 + tensor * 32768 + ks * 16384 + wave * 1024;
    size_t gk = (size_t)t * 64 + ks * 32;
#pragma unroll
    for (int s = 0; s < 2; ++s)
      gload16(g + ((size_t)srow[s] * K + gk + sk8[s] * 8), dst + s * 8192);
  };
  auto RA = [&](int t, int ks, int mf) {
    int lin = (aR + mf * 16) * 64 + kB;
    return ds128(ldsB + (t & 1) * 65536 + ks * 16384 + swzi(lin));
  };
  auto RB = [&](int t, int ks, int nf) {
    int lin = (bR + nf * 16) * 64 + kB;
    return ds128(ldsB + (t & 1) * 65536 + 32768 + ks * 16384 + swzi(lin));
  };

  // prologue: tile 0, unit order A.ks0, B.ks0, A.ks1, B.ks1
  STG(0, 0, 0); STG(0, 1, 0); STG(0, 0, 1); STG(0, 1, 1);

  for (int u = 0; u < nkt; ++u) {
    short8 bf[4], af[8];
    // ---- ph1: ks0 ----
    WAITV(4);
    BAR();
#pragma unroll
    for (int nf = 0; nf < 4; ++nf) bf[nf] = RB(u, 0, nf);
#pragma unroll
    for (int mf = 0; mf < 8; ++mf) af[mf] = RA(u, 0, mf);
    if (u + 1 < nkt) { STG(u + 1, 0, 0); STG(u + 1, 1, 0); }
    BAR(); WAITL(0); SCH0(); PRIO1();
#pragma unroll
    for (int mf = 0; mf < 8; ++mf)
#pragma unroll
      for (int nf = 0; nf < 4; ++nf) acc[mf][nf] = MF(af[mf], bf[nf], acc[mf][nf]);
    PRIO0(); SCH0();
    // ---- ph2: ks1 ----
    if (u + 1 < nkt) { WAITV(4); } else { WAITV(0); }
    BAR();
#pragma unroll
    for (int nf = 0; nf < 4; ++nf) bf[nf] = RB(u, 1, nf);
#pragma unroll
    for (int mf = 0; mf < 8; ++mf) af[mf] = RA(u, 1, mf);
    if (u + 1 < nkt) { STG(u + 1, 0, 1); STG(u + 1, 1, 1); }
    BAR(); WAITL(0); SCH0(); PRIO1();
#pragma unroll
    for (int mf = 0; mf < 8; ++mf)
#pragma unroll
      for (int nf = 0; nf < 4; ++nf) acc[mf][nf] = MF(af[mf], bf[nf], acc[mf][nf]);
    PRIO0(); SCH0();
  }

  const size_t cb = (size_t)b * sC;
  const int mB = m0 + wm * 128 + ((lane >> 4) << 2);
  const int nB = n0 + wn * 64 + (lane & 15);
#pragma unroll
  for (int mf = 0; mf < 8; ++mf)
#pragma unroll
    for (int j = 0; j < 4; ++j) {
      int m = mB + mf * 16 + j;
#pragma unroll
      for (int nf = 0; nf < 4; ++nf) {
        int n = nB + nf * 16;
        float v = acc[mf][nf][j];
        size_t o = (size_t)m * N + n;
        if (EPI == 2) outH[cb + o] = f2bf(v * scale);
        else outF[o] = (v + bias[n] + addend[o]) * scale;
      }
    }
}

// ============ split (hi/lo) GEMM, 256x256 tile, BK=32, 3 products, 3 phases/tile ============
// Per phase: {counted WAITV; BAR; ds_reads + stage; BAR; lgkm(0); 32 MFMA in setprio}.
// Stage unit order per tile: Ah,Ah,Bh,Bh (ph1), Bl,Bl,Al,Al (ph2).
// Steady waits (4)/(6)/(8); last tile (4)/(2)/(0) — queue traced unit-by-unit.
// Buffer layout (64KB): A_hi[256][32e]@0, A_lo@16K, B_hi@32K, B_lo@48K. Double buffer.
// EPI: 0 = h epilogue (bias+addend,*scale, split bf16 out), 1 = raw f32 out (scores)
template <int EPI>
__global__ __launch_bounds__(512, 2) void k_split8(
    const unsigned short* __restrict__ Ah, const unsigned short* __restrict__ Al,
    const unsigned short* __restrict__ Bh, const unsigned short* __restrict__ Bl,
    int N, int K, long sA, long sB, long sC,
    const float* __restrict__ bias, const float* __restrict__ addend,
    float* __restrict__ outF, unsigned short* __restrict__ outHi,
    unsigned short* __restrict__ outLo, float scale) {
  extern __shared__ char lds[];
  const int tid = threadIdx.x, wave = tid >> 6, lane = tid & 63;
  int L = xcd_logical();
  const int n0 = (L % gridDim.x) * 256;
  int tmpL = L / gridDim.x;
  const int m0 = (tmpL % gridDim.y) * 256;
  const int b = tmpL / gridDim.y;
  const int wm = wave >> 2, wn = wave & 3;
  const unsigned short* gb[4];
  gb[0] = Ah + (size_t)b * sA + (size_t)m0 * K;
  gb[1] = Al + (size_t)b * sA + (size_t)m0 * K;
  gb[2] = Bh + (size_t)b * sB + (size_t)n0 * K;
  gb[3] = Bl + (size_t)b * sB + (size_t)n0 * K;
  const unsigned ldsB = ldsoff(lds);

  // staging lane offsets (elements), shared by all 4 regions (16KB each, 2 slots)
  int soff[2];
#pragma unroll
  for (int s = 0; s < 2; ++s) {
    int l = swzi((s * 512 + tid) * 16);
    soff[s] = (l >> 6) * K + ((l >> 4) & 3) * 8;
  }
  const int aR = wm * 128 + (lane & 15);
  const int bR = wn * 64 + (lane & 15);
  const int kB = (lane >> 4) * 16;
  const int nkt = K >> 5;

  // hoisted swizzled ds cursors (lane part is mf/nf-invariant; toggle ^65536 per tile)
  unsigned vA = ldsB + (unsigned)swzi(aR * 64 + kB);
  unsigned vB = ldsB + (unsigned)swzi(bR * 64 + kB);

  f32x4 acc[8][4] = {};

  // stage one region (2 units) of tile t into buffer at bufbase
  auto STG2 = [&](int t, unsigned bufbase, int region) {
    char* dst = lds + bufbase + region * 16384 + tid * 16;
    const unsigned short* g = gb[region] + (size_t)t * 32;
#pragma unroll
    for (int s = 0; s < 2; ++s)
      gload16(g + soff[s], dst + s * 8192);
  };

#define TILE(u, WV1, WV2, WV3, STAGE) do {                                     \
  short8 ahi[8], bhi[4], blo[4], alo[8];                                       \
  /* ph1: hi*hi */                                                             \
  WV1; BAR();                                                                  \
  _Pragma("unroll") for (int q = 0; q < 4; ++q) bhi[q] = ds128(vB + 32768 + q * 1024); \
  _Pragma("unroll") for (int q = 0; q < 8; ++q) ahi[q] = ds128(vA + q * 1024); \
  if (STAGE) { STG2((u) + 1, nbuf, 0); STG2((u) + 1, nbuf, 2); }               \
  BAR(); WAITL(0); SCH0(); PRIO1();                                            \
  _Pragma("unroll") for (int mi = 0; mi < 8; ++mi)                             \
  _Pragma("unroll") for (int ni = 0; ni < 4; ++ni)                             \
    acc[mi][ni] = MF(ahi[mi], bhi[ni], acc[mi][ni]);                           \
  PRIO0(); SCH0();                                                             \
  /* ph2: hi*lo */                                                             \
  WV2; BAR();                                                                  \
  _Pragma("unroll") for (int q = 0; q < 4; ++q) blo[q] = ds128(vB + 49152 + q * 1024); \
  if (STAGE) { STG2((u) + 1, nbuf, 3); STG2((u) + 1, nbuf, 1); }               \
  BAR(); WAITL(0); SCH0(); PRIO1();                                            \
  _Pragma("unroll") for (int mi = 0; mi < 8; ++mi)                             \
  _Pragma("unroll") for (int ni = 0; ni < 4; ++ni)                             \
    acc[mi][ni] = MF(ahi[mi], blo[ni], acc[mi][ni]);                           \
  PRIO0(); SCH0();                                                             \
  /* ph3: lo*hi */                                                             \
  WV3; BAR();                                                                  \
  _Pragma("unroll") for (int q = 0; q < 8; ++q) alo[q] = ds128(vA + 16384 + q * 1024); \
  BAR(); WAITL(0); SCH0(); PRIO1();                                            \
  _Pragma("unroll") for (int mi = 0; mi < 8; ++mi)                             \
  _Pragma("unroll") for (int ni = 0; ni < 4; ++ni)                             \
    acc[mi][ni] = MF(alo[mi], bhi[ni], acc[mi][ni]);                           \
  PRIO0(); SCH0();                                                             \
  vA ^= 65536u; vB ^= 65536u;                                                  \
} while (0)

  // prologue: stage tile 0 into buffer 0 (unit order Ah,Ah,Bh,Bh,Bl,Bl,Al,Al)
  STG2(0, 0, 0); STG2(0, 0, 2); STG2(0, 0, 3); STG2(0, 0, 1);

  unsigned nbuf = 65536u;
  for (int u = 0; u < nkt - 1; ++u) {
    TILE(u, WAITV(4), WAITV(6), WAITV(8), 1);
    nbuf ^= 65536u;
  }
  TILE(nkt - 1, WAITV(4), WAITV(2), WAITV(0), 0);
#undef TILE

  const size_t cb = (size_t)b * sC;
  const int mB = m0 + wm * 128 + ((lane >> 4) << 2);
  const int nB = n0 + wn * 64 + (lane & 15);
#pragma unroll
  for (int mf = 0; mf < 8; ++mf)
#pragma unroll
    for (int j = 0; j < 4; ++j) {
      int m = mB + mf * 16 + j;
#pragma unroll
      for (int nf = 0; nf < 4; ++nf) {
        int n = nB + nf * 16;
        float v = acc[mf][nf][j];
        size_t o = (size_t)m * N + n;
        if (EPI == 0) {
          v = (v + bias[n] + addend[o]) * scale;
          unsigned short hb = f2bf(v);
          outHi[o] = hb;
          outLo[o] = f2bf(v - bf2f(hb));
        } else {
          outF[cb + o] = v;
        }
      }
    }
}

// ---------------- row softmax (in-place f32) + bf16 copy ----------------
__global__ __launch_bounds__(256) void k_softmax(float* __restrict__ attn,
    unsigned short* __restrict__ attn_b, const int* __restrict__ mask) {
  __shared__ float red[8];
  long r = blockIdx.x;
  int b = (int)(r >> 11);
  float* row = attn + r * (long)SS;
  const int* mrow = mask + (long)b * SS;
  int t = threadIdx.x;
  int base = t * 8;
  float v[8];
  float4 v0 = *(const float4*)(row + base);
  float4 v1 = *(const float4*)(row + base + 4);
  v[0] = v0.x; v[1] = v0.y; v[2] = v0.z; v[3] = v0.w;
  v[4] = v1.x; v[5] = v1.y; v[6] = v1.z; v[7] = v1.w;
  int4 m0i = *(const int4*)(mrow + base);
  int4 m1i = *(const int4*)(mrow + base + 4);
  int mm[8] = {m0i.x, m0i.y, m0i.z, m0i.w, m1i.x, m1i.y, m1i.z, m1i.w};
#pragma unroll
  for (int j = 0; j < 8; ++j) if (mm[j]) v[j] = -INFINITY;
  float mx = v[0];
#pragma unroll
  for (int j = 1; j < 8; ++j) mx = fmaxf(mx, v[j]);
#pragma unroll
  for (int off = 32; off; off >>= 1) mx = fmaxf(mx, __shfl_xor(mx, off));
  int wv = t >> 6, ln = t & 63;
  if (ln == 0) red[wv] = mx;
  __syncthreads();
  mx = fmaxf(fmaxf(red[0], red[1]), fmaxf(red[2], red[3]));
  float sum = 0.f;
#pragma unroll
  for (int j = 0; j < 8; ++j) { v[j] = __expf(v[j] - mx); sum += v[j]; }
#pragma unroll
  for (int off = 32; off; off >>= 1) sum += __shfl_xor(sum, off);
  if (ln == 0) red[4 + wv] = sum;
  __syncthreads();
  sum = (red[4] + red[5]) + (red[6] + red[7]);
  float inv = 1.0f / sum;
#pragma unroll
  for (int j = 0; j < 8; ++j) v[j] *= inv;
  float4 w0; w0.x = v[0]; w0.y = v[1]; w0.z = v[2]; w0.w = v[3];
  float4 w1; w1.x = v[4]; w1.y = v[5]; w1.z = v[6]; w1.w = v[7];
  *(float4*)(row + base) = w0;
  *(float4*)(row + base + 4) = w1;
  unsigned short* brow = attn_b + r * (long)SS + base;
  ushort4 h0; h0.x = f2bf(v[0]); h0.y = f2bf(v[1]); h0.z = f2bf(v[2]); h0.w = f2bf(v[3]);
  ushort4 h1; h1.x = f2bf(v[4]); h1.y = f2bf(v[5]); h1.z = f2bf(v[6]); h1.w = f2bf(v[7]);
  *(ushort4*)(brow) = h0;
  *(ushort4*)(brow + 4) = h1;
}

extern "C" void kernel_launch(void* const* d_in, const int* in_sizes, int n_in,
                              void* d_out, int out_size, void* d_ws, size_t ws_size,
                              hipStream_t stream) {
  (void)in_sizes; (void)n_in; (void)out_size; (void)ws_size;
  const float* x     = (const float*)d_in[0];
  const float* tgt   = (const float*)d_in[1];
  const float* enca  = (const float*)d_in[2];
  const float* encb  = (const float*)d_in[3];
  const int*   mask  = (const int*)d_in[4];
  const float* w_in  = (const float*)d_in[5];
  const float* b_in  = (const float*)d_in[6];
  const float* w_out = (const float*)d_in[7];
  const float* b_out = (const float*)d_in[8];

  float* out  = (float*)d_out;                       // [B,T,C]
  float* attn = out + (size_t)NB * TT * CC;          // [B,T,S]

  char* ws = (char*)d_ws;
  unsigned short* x_hi   = (unsigned short*)(ws + 0);
  unsigned short* x_lo   = (unsigned short*)(ws + 33554432L);
  unsigned short* a_t_hi = (unsigned short*)(ws + 67108864L);
  unsigned short* a_t_lo = (unsigned short*)(ws + 100663296L);
  unsigned short* b_t    = (unsigned short*)(ws + 134217728L);
  unsigned short* h_hi   = (unsigned short*)(ws + 167772160L);
  unsigned short* h_lo   = (unsigned short*)(ws + 201326592L);
  unsigned short* w_in_hi= (unsigned short*)(ws + 234881024L);
  unsigned short* w_in_lo= (unsigned short*)(ws + 236978176L);
  unsigned short* w_out_b= (unsigned short*)(ws + 239075328L);
  unsigned short* attn_b = x_hi;   // 64MB region, x dead after GEMM1
  unsigned short* pv     = h_hi;   // 32MB region, h dead after scores GEMM

  hipFuncSetAttribute(reinterpret_cast<const void*>(&k_gemm8<2>),
                      hipFuncAttributeMaxDynamicSharedMemorySize, 131072);
  hipFuncSetAttribute(reinterpret_cast<const void*>(&k_gemm8<3>),
                      hipFuncAttributeMaxDynamicSharedMemorySize, 131072);
  hipFuncSetAttribute(reinterpret_cast<const void*>(&k_split8<0>),
                      hipFuncAttributeMaxDynamicSharedMemorySize, 131072);
  hipFuncSetAttribute(reinterpret_cast<const void*>(&k_split8<1>),
                      hipFuncAttributeMaxDynamicSharedMemorySize, 131072);

  dim3 blk(256), blk512(512);
  const float S05 = 0.70710678118654752f;

  k_split<<<2048, blk, 0, stream>>>(x, x_hi, x_lo, (long)NB * TT * CC / 4);
  k_split<<<512, blk, 0, stream>>>(w_in, w_in_hi, w_in_lo, (long)EE * CC / 4);
  k_conv<<<512, blk, 0, stream>>>(w_out, w_out_b, (long)CC * EE / 4);
  k_transpose<true><<<dim3(SS / 64, EE / 64, NB), blk, 0, stream>>>(enca, a_t_hi, a_t_lo, EE, SS);
  k_transpose<false><<<dim3(EE / 64, SS / 64, NB), blk, 0, stream>>>(encb, b_t, nullptr, SS, EE);

  // GEMM1: h = (x @ w_in^T + b_in + tgt) * sqrt(0.5), split bf16 out. 256 blocks, 1 round.
  k_split8<0><<<dim3(EE / 256, (NB * TT) / 256, 1), blk512, 131072, stream>>>(
      x_hi, x_lo, w_in_hi, w_in_lo, EE, CC, 0, 0, 0,
      b_in, tgt, nullptr, h_hi, h_lo, S05);

  // scores = h @ enc_a (batched), raw f32 into attn region. 512 blocks.
  k_split8<1><<<dim3(SS / 256, TT / 256, NB), blk512, 131072, stream>>>(
      h_hi, h_lo, a_t_hi, a_t_lo, SS, EE,
      (long)TT * EE, (long)SS * EE, (long)TT * SS,
      nullptr, nullptr, attn, nullptr, nullptr, 1.0f);

  // masked softmax, in-place, + bf16 copy
  k_softmax<<<NB * TT, blk, 0, stream>>>(attn, attn_b, mask);

  // pv = (attn @ enc_b) * sqrt(S), bf16 out
  k_gemm8<2><<<dim3(EE / 256, TT / 256, NB), blk512, 131072, stream>>>(
      attn_b, b_t, EE, SS,
      (long)TT * SS, (long)EE * SS, (long)TT * EE,
      nullptr, nullptr, nullptr, pv, 45.254833995939045f);

  // out = (pv @ w_out^T + b_out + x) * sqrt(0.5)
  k_gemm8<3><<<dim3(CC / 256, (NB * TT) / 256, 1), blk512, 131072, stream>>>(
      pv, w_out_b, CC, EE, 0, 0, 0,
      b_out, x, out, nullptr, S05);
}